// Round 9
// baseline (67.067 us; speedup 1.0000x reference)
//
#include <hip/hip_runtime.h>
#include <hip/hip_fp16.h>

// GeneSymbolCNN: embed(67x32, pad0) -> conv1d k=2/3/4 (32ch) + ReLU + max_t
//                -> concat(96) -> 96x96 linear + ReLU.
// Factorization ladder:
//   R1-R8: conv-over-embedding as per-token tables T_j[v][c] (f16), LDS.
//   R9: PAIR tables P[a,b] = T_h[a] + T_{h+1}[b] (67^2=4489 entries x 64B
//       = 287KB/table, 4 tables = 1.15MB, L2-resident):
//         conv2[p] = P2[x_p,x_{p+1}]                      (15 reads, 0 adds)
//         conv3[p] = P3[x_p,x_{p+1}] + T4[x_{p+2}]        (14 glb + 14 lds)
//         conv4[p] = P4a[x_p,x_{p+1}] + P4b[x_{p+2},x_{p+3}] (26 glb)
//       Per-thread reads 124 -> 69 (55 global/L2 + 14 LDS). The 4 lanes of
//       a row read contiguous 16B chunks of one 64B entry -> coalesced.
//       One shared pair-address array pr[15] serves all 4 pair tables.
//       LDS shrinks to one table (5.4KB, 80B stride) -> occupancy capped by
//       VGPR only: __launch_bounds__(512,6) -> 24 waves/CU.
//   Projection: conv output = mfma_f32_16x16x32_f16 A-fragment directly
//       (channel-split c=lane>>4), 18 MFMAs/wave, unchanged since R6.
// Fallback: if ws_size can't hold the pair tables, run the R8 all-LDS path.

#define VOCABSZ 67
#define EMBSZ   32
#define NCH     32
#define NFEAT   96
#define SEQL    16
#define BATCH   131072
#define NTAB    9
#define NENT    (NTAB * VOCABSZ)           // 603 single-table entries
#define TABU    (NENT * NCH / 2)           // 9648 u32 words of f16 tables
#define PWOFF   TABU                       // packed pw follows tables in ws
#define NFP     (NFEAT / 2)                // 48 feature pairs
#define NPW     (NFEAT * NFP)              // 4608 packed pw words
#define PAIRW   (TABU + NPW)               // 14256: pair region start (u32)
#define NPAIR   (VOCABSZ * VOCABSZ)        // 4489 entries per pair table
#define PRW     (NPAIR * 16)               // 71824 u32 words per pair table
#define PRB     (NPAIR * 64)               // 287296 bytes per pair table
#define WSNEED  ((PAIRW + 4 * PRW) * 4)    // 1,206,208 bytes
// fallback (R8) LDS geometry
#define ESTR    80                         // LDS bytes per entry (64+16 pad)
#define LTS     (VOCABSZ * ESTR)           // 5360 B per table in LDS
#define LDSB9   LTS                        // R9: one table (T4) in LDS
#define LDSB8   (NTAB * LTS)               // R8 fallback: all 9 tables

typedef _Float16 v2h __attribute__((ext_vector_type(2)));
typedef _Float16 v8h __attribute__((ext_vector_type(8)));
typedef float    v4f __attribute__((ext_vector_type(4)));

__device__ __forceinline__ unsigned packh2(float a, float b) {
    v2h p; p[0] = (_Float16)a; p[1] = (_Float16)b;
    return __builtin_bit_cast(unsigned, p);
}

// ------------- kernel 1: f16 single tables + packed pw --------------------
__global__ __launch_bounds__(256) void build_tables(
    const float* __restrict__ embed,
    const float* __restrict__ w2, const float* __restrict__ b2,
    const float* __restrict__ w3, const float* __restrict__ b3,
    const float* __restrict__ w4, const float* __restrict__ b4,
    const float* __restrict__ pw,
    unsigned* __restrict__ ws)
{
    int idx = blockIdx.x * 256 + threadIdx.x;
    if (idx < TABU) {                      // one half2 (2 channels) per thread
        int cp = idx & 15;                 // channel pair 0..15
        int t  = idx >> 4;                 // j*67 + v
        int j  = t / VOCABSZ;
        int v  = t - j * VOCABSZ;
        const float* w; const float* bias; int k, h;
        if (j < 2)      { w = w2; k = 2; h = j;     bias = (h == 0) ? b2 : nullptr; }
        else if (j < 5) { w = w3; k = 3; h = j - 2; bias = (h == 0) ? b3 : nullptr; }
        else            { w = w4; k = 4; h = j - 5; bias = (h == 0) ? b4 : nullptr; }
        int c0 = 2 * cp;
        float a0 = bias ? bias[c0]     : 0.0f;
        float a1 = bias ? bias[c0 + 1] : 0.0f;
        if (v != 0) {                      // padding_idx=0: row 0 is zeros
            #pragma unroll
            for (int e = 0; e < EMBSZ; ++e) {
                float ev = embed[v * EMBSZ + e];
                a0 += ev * w[((c0    ) * EMBSZ + e) * k + h];
                a1 += ev * w[((c0 + 1) * EMBSZ + e) * k + h];
            }
        }
        ws[t * 16 + cp] = packh2(a0, a1);
    } else if (idx < TABU + NPW) {         // packed pw: pwh[o][fp]
        int i  = idx - TABU;
        int o  = i / NFP;
        int fp = i - o * NFP;
        ws[PWOFF + i] = packh2(pw[o * NFEAT + 2 * fp], pw[o * NFEAT + 2 * fp + 1]);
    }
}

// ------------- kernel 1b: pair tables P[a,b] = T_j0[a] + T_j0+1[b] --------
// g=0: T0+T1 (conv2); g=1: T2+T3 (conv3 taps 0,1); g=2: T5+T6; g=3: T7+T8.
__global__ __launch_bounds__(256) void build_pairs(unsigned* __restrict__ ws)
{
    int idx = blockIdx.x * 256 + threadIdx.x;
    if (idx >= 4 * PRW) return;
    int g = idx / PRW;
    int r = idx - g * PRW;
    int e = r >> 4;                        // pair entry a*67+b
    int w = r & 15;                        // u32 word within 64B entry
    int a = e / VOCABSZ;
    int b = e - a * VOCABSZ;
    int j0 = 2 * g + (g >> 1);             // 0,2,5,7
    unsigned ua = ws[((j0    ) * VOCABSZ + a) * 16 + w];
    unsigned ub = ws[((j0 + 1) * VOCABSZ + b) * 16 + w];
    v2h s = __builtin_bit_cast(v2h, ua) + __builtin_bit_cast(v2h, ub);
    ws[PAIRW + idx] = __builtin_bit_cast(unsigned, s);
}

// ------------- conv batch helpers (all indices compile-time, rule #20) ----
template<int N, int P0>                    // conv2: pure pair loads, max only
__device__ __forceinline__ void c2b(const char* __restrict__ g2,
                                    const int (&pr)[15], v8h& m)
{
    v8h s[N];
    #pragma unroll
    for (int u = 0; u < N; ++u)
        s[u] = *reinterpret_cast<const v8h*>(g2 + pr[P0 + u]);
    #pragma unroll
    for (int u = 0; u < N; ++u) m = __builtin_elementwise_max(m, s[u]);
}

template<int N, int P0>                    // conv3: pair load + LDS single
__device__ __forceinline__ void c3b(const char* __restrict__ g3,
                                    const char* __restrict__ lb,
                                    const int (&pr)[15], const int (&al)[14],
                                    v8h& m)
{
    v8h s[N], t[N];
    #pragma unroll
    for (int u = 0; u < N; ++u)
        s[u] = *reinterpret_cast<const v8h*>(g3 + pr[P0 + u]);
    #pragma unroll
    for (int u = 0; u < N; ++u)
        t[u] = *reinterpret_cast<const v8h*>(lb + al[P0 + u]);
    #pragma unroll
    for (int u = 0; u < N; ++u)
        m = __builtin_elementwise_max(m, s[u] + t[u]);
}

template<int N, int P0>                    // conv4: two pair loads
__device__ __forceinline__ void c4b(const char* __restrict__ g4a,
                                    const char* __restrict__ g4b,
                                    const int (&pr)[15], v8h& m)
{
    v8h s[N], t[N];
    #pragma unroll
    for (int u = 0; u < N; ++u)
        s[u] = *reinterpret_cast<const v8h*>(g4a + pr[P0 + u]);
    #pragma unroll
    for (int u = 0; u < N; ++u)
        t[u] = *reinterpret_cast<const v8h*>(g4b + pr[P0 + u + 2]);
    #pragma unroll
    for (int u = 0; u < N; ++u)
        m = __builtin_elementwise_max(m, s[u] + t[u]);
}

// ------------- kernel 2 (R9): pair-table conv + MFMA projection -----------
__global__ __launch_bounds__(512, 6) void fused_cnn(
    const int*      __restrict__ x,
    const unsigned* __restrict__ ws,
    const float*    __restrict__ pb,
    float*          __restrict__ out)
{
    extern __shared__ __align__(16) char ldsraw[];
    const int tid = threadIdx.x;
    {   // stage T4 (table j=4, 67 entries x 64B) at 80B stride
        const float4* s4 = reinterpret_cast<const float4*>(ws);
        float4* d4 = reinterpret_cast<float4*>(ldsraw);
        if (tid < 268) {                   // f4 idx of T4 = (4*67+v)*4+c
            int v = tid >> 2, c = tid & 3;
            d4[v * 5 + c] = s4[1072 + tid];
        }
    }
    __syncthreads();

    const int lane = tid & 63;
    const int wv   = tid >> 6;               // wave 0..7
    const int ml   = lane & 15;              // row within wave's 16-row tile
    const int c    = lane >> 4;              // fixed chunk = MFMA k-group
    const int co   = c << 4;                 // chunk byte offset in entry
    const int rowb = blockIdx.x * 128 + wv * 16;
    const int row  = rowb + ml;
    const char* lb  = ldsraw;
    const char* gp  = reinterpret_cast<const char*>(ws) + PAIRW * 4;
    const char* g2  = gp;
    const char* g3  = gp + PRB;
    const char* g4a = gp + 2 * PRB;
    const char* g4b = gp + 3 * PRB;

    const int4* xp = reinterpret_cast<const int4*>(x + row * SEQL);
    int4 q0 = xp[0], q1 = xp[1], q2 = xp[2], q3 = xp[3];
    const int t0 = q0.x, t1 = q0.y, t2 = q0.z, t3 = q0.w;
    const int t4 = q1.x, t5 = q1.y, t6 = q1.z, t7 = q1.w;
    const int t8 = q2.x, t9 = q2.y, tA = q2.z, tB = q2.w;
    const int tC = q3.x, tD = q3.y, tE = q3.z, tF = q3.w;

    int pr[15];                              // pair-entry byte offsets (+chunk)
    pr[ 0] = (t0 * VOCABSZ + t1) * 64 + co; pr[ 1] = (t1 * VOCABSZ + t2) * 64 + co;
    pr[ 2] = (t2 * VOCABSZ + t3) * 64 + co; pr[ 3] = (t3 * VOCABSZ + t4) * 64 + co;
    pr[ 4] = (t4 * VOCABSZ + t5) * 64 + co; pr[ 5] = (t5 * VOCABSZ + t6) * 64 + co;
    pr[ 6] = (t6 * VOCABSZ + t7) * 64 + co; pr[ 7] = (t7 * VOCABSZ + t8) * 64 + co;
    pr[ 8] = (t8 * VOCABSZ + t9) * 64 + co; pr[ 9] = (t9 * VOCABSZ + tA) * 64 + co;
    pr[10] = (tA * VOCABSZ + tB) * 64 + co; pr[11] = (tB * VOCABSZ + tC) * 64 + co;
    pr[12] = (tC * VOCABSZ + tD) * 64 + co; pr[13] = (tD * VOCABSZ + tE) * 64 + co;
    pr[14] = (tE * VOCABSZ + tF) * 64 + co;

    int al[14];                              // LDS byte offsets for T4[x_{p+2}]
    al[ 0] = t2 * ESTR + co; al[ 1] = t3 * ESTR + co;
    al[ 2] = t4 * ESTR + co; al[ 3] = t5 * ESTR + co;
    al[ 4] = t6 * ESTR + co; al[ 5] = t7 * ESTR + co;
    al[ 6] = t8 * ESTR + co; al[ 7] = t9 * ESTR + co;
    al[ 8] = tA * ESTR + co; al[ 9] = tB * ESTR + co;
    al[10] = tC * ESTR + co; al[11] = tD * ESTR + co;
    al[12] = tE * ESTR + co; al[13] = tF * ESTR + co;

    v8h m2 = {}, m3 = {}, m4 = {};           // feats >= 0 -> 0-init max-safe

    // interleave the three streams so VMEM and LDS pipes fill concurrently
    c2b<5,  0>(g2, pr, m2);
    c4b<5,  0>(g4a, g4b, pr, m4);
    c3b<5,  0>(g3, lb, pr, al, m3);
    c2b<5,  5>(g2, pr, m2);
    c4b<4,  5>(g4a, g4b, pr, m4);
    c3b<5,  5>(g3, lb, pr, al, m3);
    c2b<5, 10>(g2, pr, m2);
    c4b<4,  9>(g4a, g4b, pr, m4);
    c3b<4, 10>(g3, lb, pr, al, m3);

    // ---- projection: O[16 rows][96] = feat x pw^T via 18 mfma 16x16x32 ----
    const unsigned* __restrict__ pwp = ws + PWOFF + ml * NFP + c * 4;
    #pragma unroll
    for (int u = 0; u < 6; ++u) {
        v4f acc = {0.f, 0.f, 0.f, 0.f};
        v8h b0 = *reinterpret_cast<const v8h*>(pwp + 768 * u);
        v8h b1 = *reinterpret_cast<const v8h*>(pwp + 768 * u + 16);
        v8h b2 = *reinterpret_cast<const v8h*>(pwp + 768 * u + 32);
        acc = __builtin_amdgcn_mfma_f32_16x16x32_f16(m2, b0, acc, 0, 0, 0);
        acc = __builtin_amdgcn_mfma_f32_16x16x32_f16(m3, b1, acc, 0, 0, 0);
        acc = __builtin_amdgcn_mfma_f32_16x16x32_f16(m4, b2, acc, 0, 0, 0);
        float pbl = pb[16 * u + ml];
        #pragma unroll
        for (int r = 0; r < 4; ++r)
            out[(size_t)(rowb + c * 4 + r) * NFEAT + 16 * u + ml] =
                fmaxf(acc[r] + pbl, 0.f);
    }
}

// ------------- fallback kernel (R8 all-LDS), used if ws too small ---------
template<int K, int N, int P0, int TB>
__device__ __forceinline__ void lconv(const char* __restrict__ base,
                                      const int (&ap)[16], v8h& m)
{
    v8h s[N];
    #pragma unroll
    for (int u = 0; u < N; ++u)
        s[u] = *reinterpret_cast<const v8h*>(base + TB + ap[P0 + u]);
    #pragma unroll
    for (int h = 1; h < K; ++h) {
        v8h t[N];
        #pragma unroll
        for (int u = 0; u < N; ++u)
            t[u] = *reinterpret_cast<const v8h*>(base + TB + h * LTS + ap[P0 + u + h]);
        #pragma unroll
        for (int u = 0; u < N; ++u) s[u] = s[u] + t[u];
    }
    #pragma unroll
    for (int u = 0; u < N; ++u) m = __builtin_elementwise_max(m, s[u]);
}

__global__ __launch_bounds__(512, 6) void fused_cnn_fb(
    const int*      __restrict__ x,
    const unsigned* __restrict__ ws,
    const float*    __restrict__ pb,
    float*          __restrict__ out)
{
    extern __shared__ __align__(16) char ldsraw[];
    const int tid = threadIdx.x;
    {
        const float4* s4 = reinterpret_cast<const float4*>(ws);
        float4* d4 = reinterpret_cast<float4*>(ldsraw);
        #pragma unroll
        for (int i0 = 0; i0 < 2560; i0 += 512) {
            int i = i0 + tid;
            if (i < 2412) {
                int t = i >> 2, c = i & 3;
                d4[5 * t + c] = s4[i];
            }
        }
    }
    __syncthreads();

    const int lane = tid & 63;
    const int wv   = tid >> 6;
    const int ml   = lane & 15;
    const int c    = lane >> 4;
    const int co   = c << 4;
    const int rowb = blockIdx.x * 128 + wv * 16;
    const int row  = rowb + ml;
    const char* base = ldsraw;

    const int4* xp = reinterpret_cast<const int4*>(x + row * SEQL);
    int4 q0 = xp[0], q1 = xp[1], q2 = xp[2], q3 = xp[3];
    int ap[16];
    ap[ 0] = q0.x * ESTR + co; ap[ 1] = q0.y * ESTR + co;
    ap[ 2] = q0.z * ESTR + co; ap[ 3] = q0.w * ESTR + co;
    ap[ 4] = q1.x * ESTR + co; ap[ 5] = q1.y * ESTR + co;
    ap[ 6] = q1.z * ESTR + co; ap[ 7] = q1.w * ESTR + co;
    ap[ 8] = q2.x * ESTR + co; ap[ 9] = q2.y * ESTR + co;
    ap[10] = q2.z * ESTR + co; ap[11] = q2.w * ESTR + co;
    ap[12] = q3.x * ESTR + co; ap[13] = q3.y * ESTR + co;
    ap[14] = q3.z * ESTR + co; ap[15] = q3.w * ESTR + co;

    v8h m2 = {}, m3 = {}, m4 = {};
    lconv<2, 5,  0, 0 * LTS>(base, ap, m2);
    lconv<2, 5,  5, 0 * LTS>(base, ap, m2);
    lconv<2, 5, 10, 0 * LTS>(base, ap, m2);
    lconv<3, 5,  0, 2 * LTS>(base, ap, m3);
    lconv<3, 5,  5, 2 * LTS>(base, ap, m3);
    lconv<3, 4, 10, 2 * LTS>(base, ap, m3);
    lconv<4, 5,  0, 5 * LTS>(base, ap, m4);
    lconv<4, 4,  5, 5 * LTS>(base, ap, m4);
    lconv<4, 4,  9, 5 * LTS>(base, ap, m4);

    const unsigned* __restrict__ pwp = ws + PWOFF + ml * NFP + c * 4;
    #pragma unroll
    for (int u = 0; u < 6; ++u) {
        v4f acc = {0.f, 0.f, 0.f, 0.f};
        v8h b0 = *reinterpret_cast<const v8h*>(pwp + 768 * u);
        v8h b1 = *reinterpret_cast<const v8h*>(pwp + 768 * u + 16);
        v8h b2 = *reinterpret_cast<const v8h*>(pwp + 768 * u + 32);
        acc = __builtin_amdgcn_mfma_f32_16x16x32_f16(m2, b0, acc, 0, 0, 0);
        acc = __builtin_amdgcn_mfma_f32_16x16x32_f16(m3, b1, acc, 0, 0, 0);
        acc = __builtin_amdgcn_mfma_f32_16x16x32_f16(m4, b2, acc, 0, 0, 0);
        float pbl = pb[16 * u + ml];
        #pragma unroll
        for (int r = 0; r < 4; ++r)
            out[(size_t)(rowb + c * 4 + r) * NFEAT + 16 * u + ml] =
                fmaxf(acc[r] + pbl, 0.f);
    }
}

extern "C" void kernel_launch(void* const* d_in, const int* in_sizes, int n_in,
                              void* d_out, int out_size, void* d_ws, size_t ws_size,
                              hipStream_t stream)
{
    const int*   x     = (const int*)  d_in[0];
    const float* embed = (const float*)d_in[1];
    const float* w2    = (const float*)d_in[2];
    const float* b2    = (const float*)d_in[3];
    const float* w3    = (const float*)d_in[4];
    const float* b3    = (const float*)d_in[5];
    const float* w4    = (const float*)d_in[6];
    const float* b4    = (const float*)d_in[7];
    const float* pw    = (const float*)d_in[8];
    const float* pb    = (const float*)d_in[9];
    float* out = (float*)d_out;
    unsigned* ws = (unsigned*)d_ws;

    build_tables<<<(TABU + NPW + 255) / 256, 256, 0, stream>>>(
        embed, w2, b2, w3, b3, w4, b4, pw, ws);

    if (ws_size >= (size_t)WSNEED) {
        build_pairs<<<(4 * PRW + 255) / 256, 256, 0, stream>>>(ws);
        fused_cnn<<<BATCH / 128, 512, LDSB9, stream>>>(x, ws, pb, out);
    } else {
        fused_cnn_fb<<<BATCH / 128, 512, LDSB8, stream>>>(x, ws, pb, out);
    }
}

// Round 10
// 66.596 us; speedup vs baseline: 1.0071x; 1.0071x over previous
//
#include <hip/hip_runtime.h>
#include <hip/hip_fp16.h>

// GeneSymbolCNN: embed(67x32, pad0) -> conv1d k=2/3/4 (32ch) + ReLU + max_t
//                -> concat(96) -> 96x96 linear + ReLU.
// R10 = R9's pair-table dataflow + FORCED load ILP.
//   Pair tables P[a,b] = T_h[a]+T_{h+1}[b] (4 x 287KB, L2-resident):
//     conv2[p] = P2[x_p,x_{p+1}]                 15 glb reads, 0 adds
//     conv3[p] = P3[x_p,x_{p+1}] + T4[x_{p+2}]   14 glb + 14 LDS
//     conv4[p] = P4a[..] + P4b[..]               26 glb
//   R9 failed (56us, VGPR=40, VALUBusy 13%): hipcc serialized the 55 L2
//   gathers to ~2 in flight. R10 forces ILP: two named 8-load register
//   groups alternate {issue batch} sched_barrier(0) {consume other batch}
//   -- the fence pins 8-16 loads outstanding and forces both groups live.
//   __launch_bounds__(512,4) (VGPR cap 128) for the ~115-reg working set.
// Projection: conv output = mfma_f32_16x16x32_f16 A-fragment directly
//   (channel-split c=lane>>4), 18 MFMAs/wave (since R6).
// Fallback: R8 all-LDS kernel if ws is too small for pair tables.

#define VOCABSZ 67
#define EMBSZ   32
#define NCH     32
#define NFEAT   96
#define SEQL    16
#define BATCH   131072
#define NTAB    9
#define NENT    (NTAB * VOCABSZ)           // 603 single-table entries
#define TABU    (NENT * NCH / 2)           // 9648 u32 words of f16 tables
#define PWOFF   TABU                       // packed pw follows tables in ws
#define NFP     (NFEAT / 2)                // 48 feature pairs
#define NPW     (NFEAT * NFP)              // 4608 packed pw words
#define PAIRW   (TABU + NPW)               // 14256: pair region start (u32)
#define NPAIR   (VOCABSZ * VOCABSZ)        // 4489 entries per pair table
#define PRW     (NPAIR * 16)               // 71824 u32 words per pair table
#define PRB     (NPAIR * 64)               // 287296 bytes per pair table
#define WSNEED  ((PAIRW + 4 * PRW) * 4)    // 1,206,208 bytes
#define ESTR    80                         // LDS bytes per entry (64+16 pad)
#define LTS     (VOCABSZ * ESTR)           // 5360 B per table in LDS
#define LDSB9   LTS                        // R10: one table (T4) in LDS
#define LDSB8   (NTAB * LTS)               // R8 fallback: all 9 tables

typedef _Float16 v2h __attribute__((ext_vector_type(2)));
typedef _Float16 v8h __attribute__((ext_vector_type(8)));
typedef float    v4f __attribute__((ext_vector_type(4)));

#define SB()          __builtin_amdgcn_sched_barrier(0)
#define LDG(d, b, o)  d = *reinterpret_cast<const v8h*>((b) + (o))
#define LDL(d, o)     d = *reinterpret_cast<const v8h*>(lb + (o))
#define MAXA(m, v)    m = __builtin_elementwise_max(m, v)

__device__ __forceinline__ unsigned packh2(float a, float b) {
    v2h p; p[0] = (_Float16)a; p[1] = (_Float16)b;
    return __builtin_bit_cast(unsigned, p);
}

// ------------- kernel 1: f16 single tables + packed pw --------------------
__global__ __launch_bounds__(256) void build_tables(
    const float* __restrict__ embed,
    const float* __restrict__ w2, const float* __restrict__ b2,
    const float* __restrict__ w3, const float* __restrict__ b3,
    const float* __restrict__ w4, const float* __restrict__ b4,
    const float* __restrict__ pw,
    unsigned* __restrict__ ws)
{
    int idx = blockIdx.x * 256 + threadIdx.x;
    if (idx < TABU) {                      // one half2 (2 channels) per thread
        int cp = idx & 15;                 // channel pair 0..15
        int t  = idx >> 4;                 // j*67 + v
        int j  = t / VOCABSZ;
        int v  = t - j * VOCABSZ;
        const float* w; const float* bias; int k, h;
        if (j < 2)      { w = w2; k = 2; h = j;     bias = (h == 0) ? b2 : nullptr; }
        else if (j < 5) { w = w3; k = 3; h = j - 2; bias = (h == 0) ? b3 : nullptr; }
        else            { w = w4; k = 4; h = j - 5; bias = (h == 0) ? b4 : nullptr; }
        int c0 = 2 * cp;
        float a0 = bias ? bias[c0]     : 0.0f;
        float a1 = bias ? bias[c0 + 1] : 0.0f;
        if (v != 0) {                      // padding_idx=0: row 0 is zeros
            #pragma unroll
            for (int e = 0; e < EMBSZ; ++e) {
                float ev = embed[v * EMBSZ + e];
                a0 += ev * w[((c0    ) * EMBSZ + e) * k + h];
                a1 += ev * w[((c0 + 1) * EMBSZ + e) * k + h];
            }
        }
        ws[t * 16 + cp] = packh2(a0, a1);
    } else if (idx < TABU + NPW) {         // packed pw: pwh[o][fp]
        int i  = idx - TABU;
        int o  = i / NFP;
        int fp = i - o * NFP;
        ws[PWOFF + i] = packh2(pw[o * NFEAT + 2 * fp], pw[o * NFEAT + 2 * fp + 1]);
    }
}

// ------------- kernel 1b: pair tables P[a,b] = T_j0[a] + T_j0+1[b] --------
// g=0: T0+T1 (conv2); g=1: T2+T3 (conv3 taps 0,1); g=2: T5+T6; g=3: T7+T8.
__global__ __launch_bounds__(256) void build_pairs(unsigned* __restrict__ ws)
{
    int idx = blockIdx.x * 256 + threadIdx.x;
    if (idx >= 4 * PRW) return;
    int g = idx / PRW;
    int r = idx - g * PRW;
    int e = r >> 4;                        // pair entry a*67+b
    int w = r & 15;                        // u32 word within 64B entry
    int a = e / VOCABSZ;
    int b = e - a * VOCABSZ;
    int j0 = 2 * g + (g >> 1);             // 0,2,5,7
    unsigned ua = ws[((j0    ) * VOCABSZ + a) * 16 + w];
    unsigned ub = ws[((j0 + 1) * VOCABSZ + b) * 16 + w];
    v2h s = __builtin_bit_cast(v2h, ua) + __builtin_bit_cast(v2h, ub);
    ws[PAIRW + idx] = __builtin_bit_cast(unsigned, s);
}

// ------------- kernel 2 (R10): pair conv, forced-ILP + MFMA projection ----
__global__ __launch_bounds__(512, 4) void fused_cnn(
    const int*      __restrict__ x,
    const unsigned* __restrict__ ws,
    const float*    __restrict__ pb,
    float*          __restrict__ out)
{
    extern __shared__ __align__(16) char ldsraw[];
    const int tid = threadIdx.x;
    {   // stage T4 (table j=4, 67 entries x 64B) at 80B stride
        const float4* s4 = reinterpret_cast<const float4*>(ws);
        float4* d4 = reinterpret_cast<float4*>(ldsraw);
        if (tid < 268) {                   // f4 idx of T4 = (4*67+v)*4+c
            int v = tid >> 2, c = tid & 3;
            d4[v * 5 + c] = s4[1072 + tid];
        }
    }
    __syncthreads();

    const int lane = tid & 63;
    const int wv   = tid >> 6;               // wave 0..7
    const int ml   = lane & 15;              // row within wave's 16-row tile
    const int c    = lane >> 4;              // fixed chunk = MFMA k-group
    const int co   = c << 4;                 // chunk byte offset in entry
    const int rowb = blockIdx.x * 128 + wv * 16;
    const int row  = rowb + ml;
    const char* lb  = ldsraw;
    const char* gp  = reinterpret_cast<const char*>(ws) + PAIRW * 4;
    const char* g2  = gp;
    const char* g3  = gp + PRB;
    const char* g4a = gp + 2 * PRB;
    const char* g4b = gp + 3 * PRB;

    const int4* xp = reinterpret_cast<const int4*>(x + row * SEQL);
    int4 q0 = xp[0], q1 = xp[1], q2 = xp[2], q3 = xp[3];
    const int t0 = q0.x, t1 = q0.y, t2 = q0.z, t3 = q0.w;
    const int t4 = q1.x, t5 = q1.y, t6 = q1.z, t7 = q1.w;
    const int t8 = q2.x, t9 = q2.y, tA = q2.z, tB = q2.w;
    const int tC = q3.x, tD = q3.y, tE = q3.z, tF = q3.w;

    int pr[15];                              // pair-entry byte offsets (+chunk)
    pr[ 0] = (t0 * VOCABSZ + t1) * 64 + co; pr[ 1] = (t1 * VOCABSZ + t2) * 64 + co;
    pr[ 2] = (t2 * VOCABSZ + t3) * 64 + co; pr[ 3] = (t3 * VOCABSZ + t4) * 64 + co;
    pr[ 4] = (t4 * VOCABSZ + t5) * 64 + co; pr[ 5] = (t5 * VOCABSZ + t6) * 64 + co;
    pr[ 6] = (t6 * VOCABSZ + t7) * 64 + co; pr[ 7] = (t7 * VOCABSZ + t8) * 64 + co;
    pr[ 8] = (t8 * VOCABSZ + t9) * 64 + co; pr[ 9] = (t9 * VOCABSZ + tA) * 64 + co;
    pr[10] = (tA * VOCABSZ + tB) * 64 + co; pr[11] = (tB * VOCABSZ + tC) * 64 + co;
    pr[12] = (tC * VOCABSZ + tD) * 64 + co; pr[13] = (tD * VOCABSZ + tE) * 64 + co;
    pr[14] = (tE * VOCABSZ + tF) * 64 + co;

    int al[14];                              // LDS byte offsets for T4[x_{p+2}]
    al[ 0] = t2 * ESTR + co; al[ 1] = t3 * ESTR + co;
    al[ 2] = t4 * ESTR + co; al[ 3] = t5 * ESTR + co;
    al[ 4] = t6 * ESTR + co; al[ 5] = t7 * ESTR + co;
    al[ 6] = t8 * ESTR + co; al[ 7] = t9 * ESTR + co;
    al[ 8] = tA * ESTR + co; al[ 9] = tB * ESTR + co;
    al[10] = tC * ESTR + co; al[11] = tD * ESTR + co;
    al[12] = tE * ESTR + co; al[13] = tF * ESTR + co;

    v8h m2 = {}, m3 = {}, m4 = {};           // feats >= 0 -> 0-init max-safe
    v8h a0, a1, a2, a3, a4, a5, a6, a7;      // batch group A
    v8h b0, b1, b2, b3, b4, b5, b6, b7;      // batch group B

    // --- software pipeline: {issue 7-8 loads} SB {consume other batch} ---
    // A: conv2 p0..7                       // B: conv4 p0..3 (a[p], b[p+2])
    LDG(a0, g2, pr[0]); LDG(a1, g2, pr[1]); LDG(a2, g2, pr[2]); LDG(a3, g2, pr[3]);
    LDG(a4, g2, pr[4]); LDG(a5, g2, pr[5]); LDG(a6, g2, pr[6]); LDG(a7, g2, pr[7]);
    LDG(b0, g4a, pr[0]); LDG(b1, g4b, pr[2]);
    LDG(b2, g4a, pr[1]); LDG(b3, g4b, pr[3]);
    LDG(b4, g4a, pr[2]); LDG(b5, g4b, pr[4]);
    LDG(b6, g4a, pr[3]); LDG(b7, g4b, pr[5]);
    SB();
    MAXA(m2, a0); MAXA(m2, a1); MAXA(m2, a2); MAXA(m2, a3);
    MAXA(m2, a4); MAXA(m2, a5); MAXA(m2, a6); MAXA(m2, a7);
    // A2: conv2 p8..14
    LDG(a0, g2, pr[ 8]); LDG(a1, g2, pr[ 9]); LDG(a2, g2, pr[10]);
    LDG(a3, g2, pr[11]); LDG(a4, g2, pr[12]); LDG(a5, g2, pr[13]);
    LDG(a6, g2, pr[14]);
    SB();
    MAXA(m4, b0 + b1); MAXA(m4, b2 + b3); MAXA(m4, b4 + b5); MAXA(m4, b6 + b7);
    // B2: conv4 p4..7
    LDG(b0, g4a, pr[4]); LDG(b1, g4b, pr[6]);
    LDG(b2, g4a, pr[5]); LDG(b3, g4b, pr[7]);
    LDG(b4, g4a, pr[6]); LDG(b5, g4b, pr[8]);
    LDG(b6, g4a, pr[7]); LDG(b7, g4b, pr[9]);
    SB();
    MAXA(m2, a0); MAXA(m2, a1); MAXA(m2, a2); MAXA(m2, a3);
    MAXA(m2, a4); MAXA(m2, a5); MAXA(m2, a6);
    // A3: conv3 global part p0..6
    LDG(a0, g3, pr[0]); LDG(a1, g3, pr[1]); LDG(a2, g3, pr[2]);
    LDG(a3, g3, pr[3]); LDG(a4, g3, pr[4]); LDG(a5, g3, pr[5]);
    LDG(a6, g3, pr[6]);
    SB();
    MAXA(m4, b0 + b1); MAXA(m4, b2 + b3); MAXA(m4, b4 + b5); MAXA(m4, b6 + b7);
    // B3: conv4 p8..11
    LDG(b0, g4a, pr[ 8]); LDG(b1, g4b, pr[10]);
    LDG(b2, g4a, pr[ 9]); LDG(b3, g4b, pr[11]);
    LDG(b4, g4a, pr[10]); LDG(b5, g4b, pr[12]);
    LDG(b6, g4a, pr[11]); LDG(b7, g4b, pr[13]);
    SB();
    {   // conv3 combine p0..6 (LDS reads issue first inside this region)
        v8h l0, l1, l2, l3, l4, l5, l6;
        LDL(l0, al[0]); LDL(l1, al[1]); LDL(l2, al[2]); LDL(l3, al[3]);
        LDL(l4, al[4]); LDL(l5, al[5]); LDL(l6, al[6]);
        MAXA(m3, a0 + l0); MAXA(m3, a1 + l1); MAXA(m3, a2 + l2);
        MAXA(m3, a3 + l3); MAXA(m3, a4 + l4); MAXA(m3, a5 + l5);
        MAXA(m3, a6 + l6);
    }
    // A4: conv3 global part p7..13
    LDG(a0, g3, pr[ 7]); LDG(a1, g3, pr[ 8]); LDG(a2, g3, pr[ 9]);
    LDG(a3, g3, pr[10]); LDG(a4, g3, pr[11]); LDG(a5, g3, pr[12]);
    LDG(a6, g3, pr[13]);
    SB();
    MAXA(m4, b0 + b1); MAXA(m4, b2 + b3); MAXA(m4, b4 + b5); MAXA(m4, b6 + b7);
    // B4: conv4 p12
    LDG(b0, g4a, pr[12]); LDG(b1, g4b, pr[14]);
    SB();
    {   // conv3 combine p7..13
        v8h l0, l1, l2, l3, l4, l5, l6;
        LDL(l0, al[ 7]); LDL(l1, al[ 8]); LDL(l2, al[ 9]); LDL(l3, al[10]);
        LDL(l4, al[11]); LDL(l5, al[12]); LDL(l6, al[13]);
        MAXA(m3, a0 + l0); MAXA(m3, a1 + l1); MAXA(m3, a2 + l2);
        MAXA(m3, a3 + l3); MAXA(m3, a4 + l4); MAXA(m3, a5 + l5);
        MAXA(m3, a6 + l6);
    }
    SB();
    MAXA(m4, b0 + b1);

    // ---- projection: O[16 rows][96] = feat x pw^T via 18 mfma 16x16x32 ----
    const unsigned* __restrict__ pwp = ws + PWOFF + ml * NFP + c * 4;
    #pragma unroll
    for (int u = 0; u < 6; ++u) {
        v4f acc = {0.f, 0.f, 0.f, 0.f};
        v8h w0 = *reinterpret_cast<const v8h*>(pwp + 768 * u);
        v8h w1 = *reinterpret_cast<const v8h*>(pwp + 768 * u + 16);
        v8h w2 = *reinterpret_cast<const v8h*>(pwp + 768 * u + 32);
        acc = __builtin_amdgcn_mfma_f32_16x16x32_f16(m2, w0, acc, 0, 0, 0);
        acc = __builtin_amdgcn_mfma_f32_16x16x32_f16(m3, w1, acc, 0, 0, 0);
        acc = __builtin_amdgcn_mfma_f32_16x16x32_f16(m4, w2, acc, 0, 0, 0);
        float pbl = pb[16 * u + ml];
        #pragma unroll
        for (int r = 0; r < 4; ++r)
            out[(size_t)(rowb + c * 4 + r) * NFEAT + 16 * u + ml] =
                fmaxf(acc[r] + pbl, 0.f);
    }
}

// ------------- fallback kernel (R8 all-LDS), used if ws too small ---------
template<int K, int N, int P0, int TB>
__device__ __forceinline__ void lconv(const char* __restrict__ base,
                                      const int (&ap)[16], v8h& m)
{
    v8h s[N];
    #pragma unroll
    for (int u = 0; u < N; ++u)
        s[u] = *reinterpret_cast<const v8h*>(base + TB + ap[P0 + u]);
    #pragma unroll
    for (int h = 1; h < K; ++h) {
        v8h t[N];
        #pragma unroll
        for (int u = 0; u < N; ++u)
            t[u] = *reinterpret_cast<const v8h*>(base + TB + h * LTS + ap[P0 + u + h]);
        #pragma unroll
        for (int u = 0; u < N; ++u) s[u] = s[u] + t[u];
    }
    #pragma unroll
    for (int u = 0; u < N; ++u) m = __builtin_elementwise_max(m, s[u]);
}

__global__ __launch_bounds__(512, 6) void fused_cnn_fb(
    const int*      __restrict__ x,
    const unsigned* __restrict__ ws,
    const float*    __restrict__ pb,
    float*          __restrict__ out)
{
    extern __shared__ __align__(16) char ldsraw[];
    const int tid = threadIdx.x;
    {
        const float4* s4 = reinterpret_cast<const float4*>(ws);
        float4* d4 = reinterpret_cast<float4*>(ldsraw);
        #pragma unroll
        for (int i0 = 0; i0 < 2560; i0 += 512) {
            int i = i0 + tid;
            if (i < 2412) {
                int t = i >> 2, c = i & 3;
                d4[5 * t + c] = s4[i];
            }
        }
    }
    __syncthreads();

    const int lane = tid & 63;
    const int wv   = tid >> 6;
    const int ml   = lane & 15;
    const int c    = lane >> 4;
    const int co   = c << 4;
    const int rowb = blockIdx.x * 128 + wv * 16;
    const int row  = rowb + ml;
    const char* base = ldsraw;

    const int4* xp = reinterpret_cast<const int4*>(x + row * SEQL);
    int4 q0 = xp[0], q1 = xp[1], q2 = xp[2], q3 = xp[3];
    int ap[16];
    ap[ 0] = q0.x * ESTR + co; ap[ 1] = q0.y * ESTR + co;
    ap[ 2] = q0.z * ESTR + co; ap[ 3] = q0.w * ESTR + co;
    ap[ 4] = q1.x * ESTR + co; ap[ 5] = q1.y * ESTR + co;
    ap[ 6] = q1.z * ESTR + co; ap[ 7] = q1.w * ESTR + co;
    ap[ 8] = q2.x * ESTR + co; ap[ 9] = q2.y * ESTR + co;
    ap[10] = q2.z * ESTR + co; ap[11] = q2.w * ESTR + co;
    ap[12] = q3.x * ESTR + co; ap[13] = q3.y * ESTR + co;
    ap[14] = q3.z * ESTR + co; ap[15] = q3.w * ESTR + co;

    v8h m2 = {}, m3 = {}, m4 = {};
    lconv<2, 5,  0, 0 * LTS>(base, ap, m2);
    lconv<2, 5,  5, 0 * LTS>(base, ap, m2);
    lconv<2, 5, 10, 0 * LTS>(base, ap, m2);
    lconv<3, 5,  0, 2 * LTS>(base, ap, m3);
    lconv<3, 5,  5, 2 * LTS>(base, ap, m3);
    lconv<3, 4, 10, 2 * LTS>(base, ap, m3);
    lconv<4, 5,  0, 5 * LTS>(base, ap, m4);
    lconv<4, 4,  5, 5 * LTS>(base, ap, m4);
    lconv<4, 4,  9, 5 * LTS>(base, ap, m4);

    const unsigned* __restrict__ pwp = ws + PWOFF + ml * NFP + c * 4;
    #pragma unroll
    for (int u = 0; u < 6; ++u) {
        v4f acc = {0.f, 0.f, 0.f, 0.f};
        v8h w0 = *reinterpret_cast<const v8h*>(pwp + 768 * u);
        v8h w1 = *reinterpret_cast<const v8h*>(pwp + 768 * u + 16);
        v8h w2 = *reinterpret_cast<const v8h*>(pwp + 768 * u + 32);
        acc = __builtin_amdgcn_mfma_f32_16x16x32_f16(m2, w0, acc, 0, 0, 0);
        acc = __builtin_amdgcn_mfma_f32_16x16x32_f16(m3, w1, acc, 0, 0, 0);
        acc = __builtin_amdgcn_mfma_f32_16x16x32_f16(m4, w2, acc, 0, 0, 0);
        float pbl = pb[16 * u + ml];
        #pragma unroll
        for (int r = 0; r < 4; ++r)
            out[(size_t)(rowb + c * 4 + r) * NFEAT + 16 * u + ml] =
                fmaxf(acc[r] + pbl, 0.f);
    }
}

extern "C" void kernel_launch(void* const* d_in, const int* in_sizes, int n_in,
                              void* d_out, int out_size, void* d_ws, size_t ws_size,
                              hipStream_t stream)
{
    const int*   x     = (const int*)  d_in[0];
    const float* embed = (const float*)d_in[1];
    const float* w2    = (const float*)d_in[2];
    const float* b2    = (const float*)d_in[3];
    const float* w3    = (const float*)d_in[4];
    const float* b3    = (const float*)d_in[5];
    const float* w4    = (const float*)d_in[6];
    const float* b4    = (const float*)d_in[7];
    const float* pw    = (const float*)d_in[8];
    const float* pb    = (const float*)d_in[9];
    float* out = (float*)d_out;
    unsigned* ws = (unsigned*)d_ws;

    build_tables<<<(TABU + NPW + 255) / 256, 256, 0, stream>>>(
        embed, w2, b2, w3, b3, w4, b4, pw, ws);

    if (ws_size >= (size_t)WSNEED) {
        build_pairs<<<(4 * PRW + 255) / 256, 256, 0, stream>>>(ws);
        fused_cnn<<<BATCH / 128, 512, LDSB9, stream>>>(x, ws, pb, out);
    } else {
        fused_cnn_fb<<<BATCH / 128, 512, LDSB8, stream>>>(x, ws, pb, out);
    }
}

// Round 11
// 42.836 us; speedup vs baseline: 1.5657x; 1.5547x over previous
//
#include <hip/hip_runtime.h>
#include <hip/hip_fp16.h>

// GeneSymbolCNN: embed(67x32, pad0) -> conv1d k=2/3/4 (32ch) + ReLU + max_t
//                -> concat(96) -> 96x96 linear + ReLU.
// R11: GEMM-ify the convs. Key identity: the MFMA A-fragment for
// (position p, tap t) is emb[x_{p+t}] -- i.e. frag[p+t]. A wave covering
// 16 rows holds just 16 emb fragments (64 VGPR) loaded once from a
// 2-parity-replicated emb table in LDS (8.6KB, deterministically
// conflict-free: span = 4*par + c). All 248 conv MFMAs (16x16x32_f16)
// consume frag[p+t] from registers:
//   conv2: 15 pos x 2 ktiles x 2 ntiles = 60
//   conv3: 14 x 3 x 2 = 84 ; conv4: 13 x 4 x 2 = 104
// Per-thread LDS reads: 124 (R8) -> ~43. MFMA-pipe floor ~16us/CU vs R8's
// 28us LDS floor. B-fragments (conv weights) pre-packed per-lane by the
// build kernel (18KB, L1-hot, coalesced 1KB/frag). Bias via acc-init,
// ReLU via max-with-0. Conv C-layout (m89: n=lane&15, m=4*(lane>>4)+r) is
// transposed to projection A-layout through a per-wave LDS feat buffer
// (24 ds_write_b16 + 3 conflict-free ds_read_b128). Projection = R6's
// verified 18-MFMA code, unchanged. Layout conventions are the exact
// (A,B,C) triple jointly verified by R6-R8 passing absmax.
// R9/R10 lesson baked in: no scattered global gathers anywhere.

#define VOCABSZ 67
#define EMBSZ   32
#define NCH     32
#define NFEAT   96
#define SEQL    16
#define BATCH   131072
#define NFP     (NFEAT / 2)            // 48 feature pairs
// ws layout (u32 words)
#define EMBW    1072                   // 67 * 16 words  (f16 emb, row0 = 0)
#define PWOFF_W EMBW                   // packed pw: 4608 words
#define NPW     (NFEAT * NFP)
#define BFOFF_W (PWOFF_W + NPW)        // 5680: 18 B-frags * 256 words
#define NBF     18
#define WSW     (BFOFF_W + NBF * 256)  // 10288 u32 total (~41 KB)
// LDS layout (bytes)
#define EMBLDS  (VOCABSZ * 128)        // 8576: 2-parity replicated emb
#define FSTR    192                    // feat row stride: 96 f16
#define FBUF    (16 * FSTR)            // 3072 per wave
#define LDSB    (EMBLDS + 8 * FBUF)    // 33152

typedef _Float16 v2h __attribute__((ext_vector_type(2)));
typedef _Float16 v8h __attribute__((ext_vector_type(8)));
typedef float    v4f __attribute__((ext_vector_type(4)));

__device__ __forceinline__ unsigned packh2(float a, float b) {
    v2h p; p[0] = (_Float16)a; p[1] = (_Float16)b;
    return __builtin_bit_cast(unsigned, p);
}

// ------------- kernel 1: emb16 + packed pw + conv B-fragments -------------
__global__ __launch_bounds__(256) void build_ws(
    const float* __restrict__ embed,
    const float* __restrict__ w2, const float* __restrict__ w3,
    const float* __restrict__ w4, const float* __restrict__ pw,
    unsigned* __restrict__ ws)
{
    int idx = blockIdx.x * 256 + threadIdx.x;
    if (idx < EMBW) {                          // f16 emb table, row 0 zeroed
        int v = idx >> 4, wd = idx & 15;
        int e0 = 2 * wd;
        ws[idx] = (v == 0) ? 0u
                : packh2(embed[v * EMBSZ + e0], embed[v * EMBSZ + e0 + 1]);
    } else if (idx < BFOFF_W) {                // packed pw: pwh[o][fp]
        int i  = idx - PWOFF_W;
        int o  = i / NFP;
        int fp = i - o * NFP;
        ws[idx] = packh2(pw[o * NFEAT + 2 * fp], pw[o * NFEAT + 2 * fp + 1]);
    } else if (idx < WSW) {                    // conv B-frags
        int i    = idx - BFOFF_W;
        int fi   = i >> 8;                     // frag 0..17
        int l    = (i >> 2) & 63;              // lane
        int wd   = i & 3;                      // u32 word within lane's 16B
        const float* w; int k, t, nt;
        if (fi < 4)       { w = w2; k = 2; t = fi >> 1;        nt = fi & 1; }
        else if (fi < 10) { w = w3; k = 3; t = (fi - 4) >> 1;  nt = (fi - 4) & 1; }
        else              { w = w4; k = 4; t = (fi - 10) >> 1; nt = (fi - 10) & 1; }
        int ch = 16 * nt + (l & 15);           // B n-index = channel
        int e0 = 8 * (l >> 4) + 2 * wd;        // B k-index = emb dim
        ws[idx] = packh2(w[(ch * EMBSZ + e0    ) * k + t],
                         w[(ch * EMBSZ + e0 + 1) * k + t]);
    }
}

// ------------- conv GEMM: one conv, both n-tiles ---------------------------
// KT taps, NP positions, FI0 first B-frag, CJ conv index (feat block).
// All frag[] indices compile-time after unroll (rule #20).
template<int KT, int NP, int FI0, int CJ>
__device__ __forceinline__ void convmm(const v8h (&frag)[16],
                                       const char* __restrict__ bfr,
                                       const float* __restrict__ bj,
                                       char* fb, int lane)
{
    const int nl = lane & 15, g = lane >> 4;
    #pragma unroll
    for (int nt = 0; nt < 2; ++nt) {
        float bv = bj[16 * nt + nl];           // conv bias for this channel
        v8h B[KT];
        #pragma unroll
        for (int t = 0; t < KT; ++t)
            B[t] = *reinterpret_cast<const v8h*>(
                bfr + (FI0 + 2 * t + nt) * 1024 + lane * 16);
        v4f mx = {0.f, 0.f, 0.f, 0.f};         // ReLU folded: max with 0
        #pragma unroll
        for (int p = 0; p < NP; ++p) {
            v4f acc = {bv, bv, bv, bv};
            #pragma unroll
            for (int t = 0; t < KT; ++t)
                acc = __builtin_amdgcn_mfma_f32_16x16x32_f16(
                    frag[p + t], B[t], acc, 0, 0, 0);
            mx = __builtin_elementwise_max(mx, acc);
        }
        // C-layout: n = nl (channel), m = 4g + r. Write f16 to feat buffer.
        #pragma unroll
        for (int r = 0; r < 4; ++r)
            *reinterpret_cast<_Float16*>(
                fb + (4 * g + r) * FSTR + (CJ * 32 + 16 * nt + nl) * 2) =
                (_Float16)mx[r];
    }
}

// ------------- kernel 2: fused conv-GEMM + transpose + projection ---------
__global__ __launch_bounds__(512, 3) void fused_cnn(
    const int*      __restrict__ x,
    const unsigned* __restrict__ ws,
    const float*    __restrict__ b2,
    const float*    __restrict__ b3,
    const float*    __restrict__ b4,
    const float*    __restrict__ pb,
    float*          __restrict__ out)
{
    extern __shared__ __align__(16) char lds[];
    const int tid = threadIdx.x;
    {   // stage emb16 (268 f4) with 2-parity replication (128B lines)
        const float4* s4 = reinterpret_cast<const float4*>(ws);
        float4* d4 = reinterpret_cast<float4*>(lds);
        if (tid < 268) {
            int v = tid >> 2, cw = tid & 3;
            float4 e = s4[tid];
            d4[v * 8 + cw]     = e;            // parity 0
            d4[v * 8 + 4 + cw] = e;            // parity 1 (+64 B)
        }
    }
    __syncthreads();

    const int lane = tid & 63;
    const int wv   = tid >> 6;                 // wave 0..7
    const int ml   = lane & 15;                // batch row within wave tile
    const int c    = lane >> 4;                // k-group (A-frag chunk)
    const int parc = (((lane >> 3) & 1) << 6) + (c << 4);  // conflict-free
    const int rowb = blockIdx.x * 128 + wv * 16;
    const int row  = rowb + ml;
    char* fb = lds + EMBLDS + wv * FBUF;       // wave-private feat buffer
    const char* bfr = reinterpret_cast<const char*>(ws + BFOFF_W);

    // tokens of this lane's row (4 c-threads duplicate the load; L1-hot)
    const int4* xp = reinterpret_cast<const int4*>(x + row * SEQL);
    int4 q0 = xp[0], q1 = xp[1], q2 = xp[2], q3 = xp[3];
    int tq[16];
    tq[ 0] = q0.x; tq[ 1] = q0.y; tq[ 2] = q0.z; tq[ 3] = q0.w;
    tq[ 4] = q1.x; tq[ 5] = q1.y; tq[ 6] = q1.z; tq[ 7] = q1.w;
    tq[ 8] = q2.x; tq[ 9] = q2.y; tq[10] = q2.z; tq[11] = q2.w;
    tq[12] = q3.x; tq[13] = q3.y; tq[14] = q3.z; tq[15] = q3.w;

    // 16 A-fragments: frag[q] = emb[x_row[q]][8c..8c+7]; zero bank conflicts
    v8h frag[16];
    #pragma unroll
    for (int q = 0; q < 16; ++q)
        frag[q] = *reinterpret_cast<const v8h*>(lds + (tq[q] << 7) + parc);

    // conv GEMMs: 60 + 84 + 104 MFMAs, feats land in fb via C-layout writes
    convmm<2, 15,  0, 0>(frag, bfr, b2, fb, lane);
    convmm<3, 14,  4, 1>(frag, bfr, b3, fb, lane);
    convmm<4, 13, 10, 2>(frag, bfr, b4, fb, lane);

    // read back in projection A-layout (conflict-free: span = c + 4*(ml&1))
    v8h m2 = *reinterpret_cast<const v8h*>(fb + ml * FSTR +       (c << 4));
    v8h m3 = *reinterpret_cast<const v8h*>(fb + ml * FSTR +  64 + (c << 4));
    v8h m4 = *reinterpret_cast<const v8h*>(fb + ml * FSTR + 128 + (c << 4));

    // ---- projection: O[16 rows][96] via 18 MFMAs (R6-verified) ----
    const unsigned* __restrict__ pwp = ws + PWOFF_W + ml * NFP + c * 4;
    #pragma unroll
    for (int u = 0; u < 6; ++u) {
        v4f acc = {0.f, 0.f, 0.f, 0.f};
        v8h w0 = *reinterpret_cast<const v8h*>(pwp + 768 * u);
        v8h w1 = *reinterpret_cast<const v8h*>(pwp + 768 * u + 16);
        v8h w2 = *reinterpret_cast<const v8h*>(pwp + 768 * u + 32);
        acc = __builtin_amdgcn_mfma_f32_16x16x32_f16(m2, w0, acc, 0, 0, 0);
        acc = __builtin_amdgcn_mfma_f32_16x16x32_f16(m3, w1, acc, 0, 0, 0);
        acc = __builtin_amdgcn_mfma_f32_16x16x32_f16(m4, w2, acc, 0, 0, 0);
        float pbl = pb[16 * u + ml];
        #pragma unroll
        for (int r = 0; r < 4; ++r)
            out[(size_t)(rowb + c * 4 + r) * NFEAT + 16 * u + ml] =
                fmaxf(acc[r] + pbl, 0.f);
    }
}

extern "C" void kernel_launch(void* const* d_in, const int* in_sizes, int n_in,
                              void* d_out, int out_size, void* d_ws, size_t ws_size,
                              hipStream_t stream)
{
    const int*   x     = (const int*)  d_in[0];
    const float* embed = (const float*)d_in[1];
    const float* w2    = (const float*)d_in[2];
    const float* b2    = (const float*)d_in[3];
    const float* w3    = (const float*)d_in[4];
    const float* b3    = (const float*)d_in[5];
    const float* w4    = (const float*)d_in[6];
    const float* b4    = (const float*)d_in[7];
    const float* pw    = (const float*)d_in[8];
    const float* pb    = (const float*)d_in[9];
    float* out = (float*)d_out;
    unsigned* ws = (unsigned*)d_ws;            // ~41 KB used

    build_ws<<<(WSW + 255) / 256, 256, 0, stream>>>(embed, w2, w3, w4, pw, ws);

    // 4 threads/row, 128 rows/block -> grid 1024; LDS 33.2KB; VGPR cap 170
    // (launch_bounds 512,3) -> 24 waves/CU; MFMA-pipe-bound by design.
    fused_cnn<<<BATCH / 128, 512, LDSB, stream>>>(x, ws, b2, b3, b4, pb, out);
}

// Round 12
// 42.202 us; speedup vs baseline: 1.5892x; 1.0150x over previous
//
#include <hip/hip_runtime.h>
#include <hip/hip_fp16.h>

// GeneSymbolCNN: embed(67x32, pad0) -> conv1d k=2/3/4 (32ch) + ReLU + max_t
//                -> concat(96) -> 96x96 linear + ReLU.
// R12 = R11 (conv as MFMA over shared emb fragments: frag[p+t] identity,
// 248 conv MFMAs + 18 proj MFMAs per wave) with the three R11 stall
// suspects removed:
//  (a) conv B-fragments staged to LDS (was global: 18KB bfr + 18KB pw +
//      emb > 32KB L1 -> thrash, ~200cyc misses feeding MFMAs). Reads are
//      base + lane*16: stride-1, conflict-free. pw now owns L1.
//  (b) __launch_bounds__(512,2): VGPR cap 256 (was 170 at (512,3), right
//      at the ~150-reg unrolled working set -> possible chain
//      serialization, the R7/R9 squeeze signature). 2 blocks/CU = 16
//      waves; R6 proved 16 waves suffice.
//  (c) feat-buffer stride 192->208B (52 dwords, 16B-aligned): read-back
//      bank pattern ml*52 mod 32 has period 8 -> 2-way max (free); was
//      8-way at 192B.
//  (d) x-row tokens prefetched before the staging loop (cold-HBM hide).
// LDS: emb 8576 + bfr 18432 + 8 wave-private fb 3328 = 53632 B.

#define VOCABSZ 67
#define EMBSZ   32
#define NCH     32
#define NFEAT   96
#define SEQL    16
#define BATCH   131072
#define NFP     (NFEAT / 2)            // 48 feature pairs
// ws layout (u32 words)
#define EMBW    1072                   // 67 * 16 words  (f16 emb, row0 = 0)
#define PWOFF_W EMBW                   // packed pw: 4608 words
#define NPW     (NFEAT * NFP)
#define BFOFF_W (PWOFF_W + NPW)        // 5680: 18 B-frags * 256 words
#define NBF     18
#define WSW     (BFOFF_W + NBF * 256)  // 10288 u32 total (~41 KB)
// LDS layout (bytes)
#define EMBLDS  (VOCABSZ * 128)        // 8576: 2-parity replicated emb
#define BFLDS   (NBF * 1024)           // 18432: conv B-fragments
#define FBOFF   (EMBLDS + BFLDS)       // 27008
#define FSTR    208                    // feat row stride (13*16B; 52 dwords)
#define FBUF    (16 * FSTR)            // 3328 per wave
#define LDSB    (FBOFF + 8 * FBUF)     // 53632

typedef _Float16 v2h __attribute__((ext_vector_type(2)));
typedef _Float16 v8h __attribute__((ext_vector_type(8)));
typedef float    v4f __attribute__((ext_vector_type(4)));

__device__ __forceinline__ unsigned packh2(float a, float b) {
    v2h p; p[0] = (_Float16)a; p[1] = (_Float16)b;
    return __builtin_bit_cast(unsigned, p);
}

// ------------- kernel 1: emb16 + packed pw + conv B-fragments -------------
__global__ __launch_bounds__(256) void build_ws(
    const float* __restrict__ embed,
    const float* __restrict__ w2, const float* __restrict__ w3,
    const float* __restrict__ w4, const float* __restrict__ pw,
    unsigned* __restrict__ ws)
{
    int idx = blockIdx.x * 256 + threadIdx.x;
    if (idx < EMBW) {                          // f16 emb table, row 0 zeroed
        int v = idx >> 4, wd = idx & 15;
        int e0 = 2 * wd;
        ws[idx] = (v == 0) ? 0u
                : packh2(embed[v * EMBSZ + e0], embed[v * EMBSZ + e0 + 1]);
    } else if (idx < BFOFF_W) {                // packed pw: pwh[o][fp]
        int i  = idx - PWOFF_W;
        int o  = i / NFP;
        int fp = i - o * NFP;
        ws[idx] = packh2(pw[o * NFEAT + 2 * fp], pw[o * NFEAT + 2 * fp + 1]);
    } else if (idx < WSW) {                    // conv B-frags
        int i    = idx - BFOFF_W;
        int fi   = i >> 8;                     // frag 0..17
        int l    = (i >> 2) & 63;              // lane
        int wd   = i & 3;                      // u32 word within lane's 16B
        const float* w; int k, t, nt;
        if (fi < 4)       { w = w2; k = 2; t = fi >> 1;        nt = fi & 1; }
        else if (fi < 10) { w = w3; k = 3; t = (fi - 4) >> 1;  nt = (fi - 4) & 1; }
        else              { w = w4; k = 4; t = (fi - 10) >> 1; nt = (fi - 10) & 1; }
        int ch = 16 * nt + (l & 15);           // B n-index = channel
        int e0 = 8 * (l >> 4) + 2 * wd;        // B k-index = emb dim
        ws[idx] = packh2(w[(ch * EMBSZ + e0    ) * k + t],
                         w[(ch * EMBSZ + e0 + 1) * k + t]);
    }
}

// ------------- conv GEMM: one conv, both n-tiles ---------------------------
// KT taps, NP positions, FI0 first B-frag, CJ conv index (feat block).
// All frag[] indices compile-time after unroll (rule #20). B from LDS.
template<int KT, int NP, int FI0, int CJ>
__device__ __forceinline__ void convmm(const v8h (&frag)[16],
                                       const char* __restrict__ lds,
                                       const float* __restrict__ bj,
                                       char* fb, int lane)
{
    const int nl = lane & 15, g = lane >> 4;
    #pragma unroll
    for (int nt = 0; nt < 2; ++nt) {
        float bv = bj[16 * nt + nl];           // conv bias for this channel
        v8h B[KT];
        #pragma unroll
        for (int t = 0; t < KT; ++t)
            B[t] = *reinterpret_cast<const v8h*>(
                lds + EMBLDS + (FI0 + 2 * t + nt) * 1024 + lane * 16);
        v4f mx = {0.f, 0.f, 0.f, 0.f};         // ReLU folded: max with 0
        #pragma unroll
        for (int p = 0; p < NP; ++p) {
            v4f acc = {bv, bv, bv, bv};
            #pragma unroll
            for (int t = 0; t < KT; ++t)
                acc = __builtin_amdgcn_mfma_f32_16x16x32_f16(
                    frag[p + t], B[t], acc, 0, 0, 0);
            mx = __builtin_elementwise_max(mx, acc);
        }
        // C-layout: n = nl (channel), m = 4g + r. Write f16 to feat buffer.
        #pragma unroll
        for (int r = 0; r < 4; ++r)
            *reinterpret_cast<_Float16*>(
                fb + (4 * g + r) * FSTR + (CJ * 32 + 16 * nt + nl) * 2) =
                (_Float16)mx[r];
    }
}

// ------------- kernel 2: fused conv-GEMM + transpose + projection ---------
__global__ __launch_bounds__(512, 2) void fused_cnn(
    const int*      __restrict__ x,
    const unsigned* __restrict__ ws,
    const float*    __restrict__ b2,
    const float*    __restrict__ b3,
    const float*    __restrict__ b4,
    const float*    __restrict__ pb,
    float*          __restrict__ out)
{
    extern __shared__ __align__(16) char lds[];
    const int tid  = threadIdx.x;
    const int lane = tid & 63;
    const int wv   = tid >> 6;                 // wave 0..7
    const int ml   = lane & 15;                // batch row within wave tile
    const int c    = lane >> 4;                // k-group (A-frag chunk)
    const int parc = (((lane >> 3) & 1) << 6) + (c << 4);  // conflict-free
    const int rowb = blockIdx.x * 128 + wv * 16;
    const int row  = rowb + ml;

    // (d) prefetch this lane's row tokens before staging (hide HBM latency)
    const int4* xp = reinterpret_cast<const int4*>(x + row * SEQL);
    int4 q0 = xp[0], q1 = xp[1], q2 = xp[2], q3 = xp[3];

    {   // stage emb16 (268 f4, 2-parity replicated) + B-frags (1152 f4)
        const float4* s4 = reinterpret_cast<const float4*>(ws);
        float4* d4 = reinterpret_cast<float4*>(lds);
        if (tid < 268) {
            int v = tid >> 2, cw = tid & 3;
            float4 e = s4[tid];
            d4[v * 8 + cw]     = e;            // parity 0
            d4[v * 8 + 4 + cw] = e;            // parity 1 (+64 B)
        }
        const float4* sb = reinterpret_cast<const float4*>(ws + BFOFF_W);
        float4* db = reinterpret_cast<float4*>(lds + EMBLDS);
        db[tid]       = sb[tid];
        db[tid + 512] = sb[tid + 512];
        if (tid < 128) db[tid + 1024] = sb[tid + 1024];
    }
    __syncthreads();

    char* fb = lds + FBOFF + wv * FBUF;        // wave-private feat buffer

    int tq[16];
    tq[ 0] = q0.x; tq[ 1] = q0.y; tq[ 2] = q0.z; tq[ 3] = q0.w;
    tq[ 4] = q1.x; tq[ 5] = q1.y; tq[ 6] = q1.z; tq[ 7] = q1.w;
    tq[ 8] = q2.x; tq[ 9] = q2.y; tq[10] = q2.z; tq[11] = q2.w;
    tq[12] = q3.x; tq[13] = q3.y; tq[14] = q3.z; tq[15] = q3.w;

    // 16 A-fragments: frag[q] = emb[x_row[q]][8c..8c+7]; zero bank conflicts
    v8h frag[16];
    #pragma unroll
    for (int q = 0; q < 16; ++q)
        frag[q] = *reinterpret_cast<const v8h*>(lds + (tq[q] << 7) + parc);

    // conv GEMMs: 60 + 84 + 104 MFMAs, feats land in fb via C-layout writes
    convmm<2, 15,  0, 0>(frag, lds, b2, fb, lane);
    convmm<3, 14,  4, 1>(frag, lds, b3, fb, lane);
    convmm<4, 13, 10, 2>(frag, lds, b4, fb, lane);

    // read back in projection A-layout (FSTR=208: 2-way max, free)
    v8h m2 = *reinterpret_cast<const v8h*>(fb + ml * FSTR +       (c << 4));
    v8h m3 = *reinterpret_cast<const v8h*>(fb + ml * FSTR +  64 + (c << 4));
    v8h m4 = *reinterpret_cast<const v8h*>(fb + ml * FSTR + 128 + (c << 4));

    // ---- projection: O[16 rows][96] via 18 MFMAs (R6-verified) ----
    const unsigned* __restrict__ pwp = ws + PWOFF_W + ml * NFP + c * 4;
    #pragma unroll
    for (int u = 0; u < 6; ++u) {
        v4f acc = {0.f, 0.f, 0.f, 0.f};
        v8h w0 = *reinterpret_cast<const v8h*>(pwp + 768 * u);
        v8h w1 = *reinterpret_cast<const v8h*>(pwp + 768 * u + 16);
        v8h w2 = *reinterpret_cast<const v8h*>(pwp + 768 * u + 32);
        acc = __builtin_amdgcn_mfma_f32_16x16x32_f16(m2, w0, acc, 0, 0, 0);
        acc = __builtin_amdgcn_mfma_f32_16x16x32_f16(m3, w1, acc, 0, 0, 0);
        acc = __builtin_amdgcn_mfma_f32_16x16x32_f16(m4, w2, acc, 0, 0, 0);
        float pbl = pb[16 * u + ml];
        #pragma unroll
        for (int r = 0; r < 4; ++r)
            out[(size_t)(rowb + c * 4 + r) * NFEAT + 16 * u + ml] =
                fmaxf(acc[r] + pbl, 0.f);
    }
}

extern "C" void kernel_launch(void* const* d_in, const int* in_sizes, int n_in,
                              void* d_out, int out_size, void* d_ws, size_t ws_size,
                              hipStream_t stream)
{
    const int*   x     = (const int*)  d_in[0];
    const float* embed = (const float*)d_in[1];
    const float* w2    = (const float*)d_in[2];
    const float* b2    = (const float*)d_in[3];
    const float* w3    = (const float*)d_in[4];
    const float* b3    = (const float*)d_in[5];
    const float* w4    = (const float*)d_in[6];
    const float* b4    = (const float*)d_in[7];
    const float* pw    = (const float*)d_in[8];
    const float* pb    = (const float*)d_in[9];
    float* out = (float*)d_out;
    unsigned* ws = (unsigned*)d_ws;            // ~41 KB used

    build_ws<<<(WSW + 255) / 256, 256, 0, stream>>>(embed, w2, w3, w4, pw, ws);

    // 4 threads/row, 128 rows/block -> grid 1024; LDS 53.6KB (2 blocks/CU,
    // 16 waves); VGPR cap 256 (launch_bounds 512,2).
    fused_cnn<<<BATCH / 128, 512, LDSB, stream>>>(x, ws, b2, b3, b4, pb, out);
}